// Round 3
// baseline (525.551 us; speedup 1.0000x reference)
//
#include <hip/hip_runtime.h>

// MADGraph scoring kernel, MI355X (gfx950).
// One wave (64 lanes) per query. Lane layout: sgrp = lane>>4 (4 sample groups
// == DPP rows), d16 = lane&15 (16 dim-blocks of 8 floats -> 128 dims).
// R2: 16-lane reductions via DPP (VALU pipe) instead of ds_swizzle shuffles.

#define D 128
#define S 8

// DPP-based add-reduce helper: x += x[src_lane(ctrl)] within the 16-lane DPP row.
template <int CTRL>
__device__ __forceinline__ float dpp_add(float x) {
    int t = __builtin_amdgcn_update_dpp(0, __float_as_int(x), CTRL, 0xF, 0xF, true);
    return x + __int_as_float(t);
}

// Full 16-lane row reduction: quad_perm xor1 (0xB1), xor2 (0x4E),
// then row_ror:4 (0x124), row_ror:8 (0x128). All lanes end with the row sum.
__device__ __forceinline__ float row16_sum(float x) {
    x = dpp_add<0xB1>(x);
    x = dpp_add<0x4E>(x);
    x = dpp_add<0x124>(x);
    x = dpp_add<0x128>(x);
    return x;
}

__global__ __launch_bounds__(256, 4) void madgraph_kernel(
    const int* __restrict__ src, const int* __restrict__ dst,
    const int* __restrict__ mid0, const int* __restrict__ mid1,
    const float* __restrict__ position, const float* __restrict__ src_field,
    const float* __restrict__ dst_field, const float* __restrict__ unc,
    const float* __restrict__ edge, float* __restrict__ out,
    int n_query, int n_nodes)
{
    const int lane = threadIdx.x & 63;
    const int wave = threadIdx.x >> 6;
    const int n = blockIdx.x * 4 + wave;
    if (n >= n_query) return;

    const int d16  = lane & 15;
    const int sgrp = lane >> 4;
    const int dbase = d16 * 8;

    // ---- phase 1: issue EVERY load up front ----
    const int sn = src[n];
    const int dn = dst[n];
    const float U = unc[0];

    const int m00 = mid0[(size_t)n * S + sgrp];
    const int m01 = mid0[(size_t)n * S + 4 + sgrp];
    const int m10 = mid1[(size_t)n * S + sgrp];
    const int m11 = mid1[(size_t)n * S + 4 + sgrp];

    // edge scalars — random into 400 MB, no reuse: nontemporal spares the LLC
    const float e0 = __builtin_nontemporal_load(edge + (size_t)m00 * n_nodes + dn);
    const float e1 = __builtin_nontemporal_load(edge + (size_t)m01 * n_nodes + dn);
    const float e2 = __builtin_nontemporal_load(edge + (size_t)sn * n_nodes + m10);
    const float e3 = __builtin_nontemporal_load(edge + (size_t)sn * n_nodes + m11);

    const float4* pS = (const float4*)(position  + (size_t)sn * D + dbase);
    const float4* pD = (const float4*)(position  + (size_t)dn * D + dbase);
    const float4* fD = (const float4*)(dst_field + (size_t)dn * D + dbase);
    const float4* fS = (const float4*)(src_field + (size_t)sn * D + dbase);
    const float4 ps0 = pS[0], ps1 = pS[1];
    const float4 pd0 = pD[0], pd1 = pD[1];
    const float4 fd0 = fD[0], fd1 = fD[1];
    const float4 fs0 = fS[0], fs1 = fS[1];

    const float4* q0 = (const float4*)(position + (size_t)m00 * D + dbase);
    const float4* q1 = (const float4*)(position + (size_t)m01 * D + dbase);
    const float4* q2 = (const float4*)(position + (size_t)m10 * D + dbase);
    const float4* q3 = (const float4*)(position + (size_t)m11 * D + dbase);
    const float4 a0 = q0[0], a1 = q0[1];
    const float4 b0 = q1[0], b1 = q1[1];
    const float4 c0 = q2[0], c1 = q2[1];
    const float4 g0 = q3[0], g1 = q3[1];

    // ---- phase 2: 4 independent dot/sq chains ----
    float dot0 = 0.f, sq0 = 0.f, dot1 = 0.f, sq1 = 0.f;
    float dot2 = 0.f, sq2 = 0.f, dot3 = 0.f, sq3 = 0.f;
    float t;
#define ACC(dotv, sqv, r, m, f) \
    t = r.x - m.x; dotv += t * f.x; sqv += t * t; \
    t = r.y - m.y; dotv += t * f.y; sqv += t * t; \
    t = r.z - m.z; dotv += t * f.z; sqv += t * t; \
    t = r.w - m.w; dotv += t * f.w; sqv += t * t;

    ACC(dot0, sq0, ps0, a0, fd0) ACC(dot0, sq0, ps1, a1, fd1)   // side0 s=sgrp
    ACC(dot1, sq1, ps0, b0, fd0) ACC(dot1, sq1, ps1, b1, fd1)   // side0 s=4+sgrp
    ACC(dot2, sq2, pd0, c0, fs0) ACC(dot2, sq2, pd1, c1, fs1)   // side1 s=sgrp
    ACC(dot3, sq3, pd0, g0, fs0) ACC(dot3, sq3, pd1, g1, fs1)   // side1 s=4+sgrp
#undef ACC

    // ---- 16-lane row reductions on the VALU pipe (DPP) ----
    dot0 = row16_sum(dot0);  sq0 = row16_sum(sq0);
    dot1 = row16_sum(dot1);  sq1 = row16_sum(sq1);
    dot2 = row16_sum(dot2);  sq2 = row16_sum(sq2);
    dot3 = row16_sum(dot3);  sq3 = row16_sum(sq3);

    float logit[4], xs[4];
    logit[0] = dot0 + U * e0;  xs[0] = 1.0f - sqrtf(sq0);
    logit[1] = dot1 + U * e1;  xs[1] = 1.0f - sqrtf(sq1);
    logit[2] = dot2 + U * e2;  xs[2] = 1.0f - sqrtf(sq2);
    logit[3] = dot3 + U * e3;  xs[3] = 1.0f - sqrtf(sq3);

    // softmax over 16 samples: 4 in registers, 4 groups across lane bits 4-5
    float m = fmaxf(fmaxf(xs[0], xs[1]), fmaxf(xs[2], xs[3]));
    m = fmaxf(m, __shfl_xor(m, 16, 64));
    m = fmaxf(m, __shfl_xor(m, 32, 64));

    float se = 0.f, sa = 0.f;
    #pragma unroll
    for (int p = 0; p < 4; ++p) {
        const float w = __expf(xs[p] - m);
        se += w;
        sa += w * logit[p];
    }
    se += __shfl_xor(se, 16, 64);
    sa += __shfl_xor(sa, 16, 64);
    se += __shfl_xor(se, 32, 64);
    sa += __shfl_xor(sa, 32, 64);

    if (lane == 0) out[n] = sa / se;
}

extern "C" void kernel_launch(void* const* d_in, const int* in_sizes, int n_in,
                              void* d_out, int out_size, void* d_ws, size_t ws_size,
                              hipStream_t stream)
{
    const int*   src      = (const int*)d_in[0];
    const int*   dst      = (const int*)d_in[1];
    const int*   mid0     = (const int*)d_in[2];
    const int*   mid1     = (const int*)d_in[3];
    const float* position = (const float*)d_in[4];
    const float* srcf     = (const float*)d_in[5];
    const float* dstf     = (const float*)d_in[6];
    const float* unc      = (const float*)d_in[7];
    const float* edge     = (const float*)d_in[8];
    float*       out      = (float*)d_out;

    const int n_query = in_sizes[0];
    const int n_nodes = in_sizes[4] / D;

    const int grid = (n_query + 3) / 4;   // 4 waves (queries) per 256-thread block

    madgraph_kernel<<<grid, 256, 0, stream>>>(
        src, dst, mid0, mid1, position, srcf, dstf, unc, edge, out,
        n_query, n_nodes);
}